// Round 3
// baseline (1006.620 us; speedup 1.0000x reference)
//
#include <hip/hip_runtime.h>

#define NNODE 100000
#define NEDGE 1000000
#define CAP 64

__device__ __forceinline__ float lrelu(float x){ return x >= 0.f ? x : 0.2f*x; }

// ---- graph build ---------------------------------------------------------
__global__ void detect_kernel(const int* __restrict__ ei, int* __restrict__ flag){
    if (threadIdx.x == 0 && blockIdx.x == 0){
        int nz = 0;
        for (int i = 1; i < 64; i += 2) nz |= ei[i];
        flag[0] = (nz == 0) ? 1 : 0;   // 1 => data is int64
    }
}

__global__ __launch_bounds__(256) void scatter_kernel(const int* __restrict__ ei,
                                                      const int* __restrict__ flag,
                                                      int* __restrict__ cnt,
                                                      int* __restrict__ col){
    int e = blockIdx.x * 256 + threadIdx.x;
    if (e >= NEDGE) return;
    int s, d;
    if (flag[0]){ s = ei[2*e]; d = ei[2*(NEDGE + e)]; }
    else        { s = ei[e];   d = ei[NEDGE + e]; }
    if ((unsigned)s < NNODE && (unsigned)d < NNODE){
        int p = atomicAdd(&cnt[d], 1);
        if (p < CAP) col[d*CAP + p] = s;
    }
}

__global__ __launch_bounds__(256) void dinv_kernel(const int* __restrict__ cnt,
                                                   float* __restrict__ dinv){
    int i = blockIdx.x * 256 + threadIdx.x;
    if (i < NNODE) dinv[i] = rsqrtf((float)(cnt[i] + 1));
}

// ---- SSGConv gather: h = 0.5*x + 0.5*agg ---------------------------------
__global__ __launch_bounds__(256) void ssg_kernel(const float* __restrict__ x,
                                                  const int* __restrict__ col,
                                                  const int* __restrict__ cnt,
                                                  const float* __restrict__ dinv,
                                                  float* __restrict__ h){
    int wid = threadIdx.x >> 6, lane = threadIdx.x & 63;
    int d = blockIdx.x * 4 + wid;
    float di = dinv[d];
    float xd = x[(size_t)d*64 + lane];
    float acc = xd * di * di;                       // self loop
    int degd = min(cnt[d], CAP);
    int myc = (lane < degd) ? col[d*CAP + lane] : 0;
    for (int k = 0; k < degd; ++k){
        int s = __shfl(myc, k);
        acc = fmaf(x[(size_t)s*64 + lane], dinv[s]*di, acc);
    }
    h[(size_t)d*64 + lane] = 0.5f*xd + 0.5f*acc;
}

// ---- small f32 GEMM: Y[N,OUT] = X[N,K] @ W[K,OUT] + B --------------------
template<int K, int OUT>
__global__ __launch_bounds__(256) void gemm_kernel(const float* __restrict__ X,
                                                   const float* __restrict__ W,
                                                   const float* __restrict__ B,
                                                   float* __restrict__ Y){
    __shared__ float Xs[64][65];
    __shared__ float Ws[64][64];
    int row0 = blockIdx.x * 64, col0 = blockIdx.y * 64;
    int tid = threadIdx.x;
    int tc = tid & 15, tr = tid >> 4;
    int r0 = tr * 4, c0 = tc * 4;
    float acc[4][4] = {};
    for (int k0 = 0; k0 < K; k0 += 64){
        int kb = K - k0; if (kb > 64) kb = 64;
        for (int t = tid; t < 64*64; t += 256){
            int r = t >> 6, k = t & 63;
            int gr = row0 + r;
            Xs[r][k] = (k < kb && gr < NNODE) ? X[(size_t)gr*K + k0 + k] : 0.f;
        }
        for (int t = tid; t < 64*64; t += 256){
            int k = t >> 6, c = t & 63;
            int gc = col0 + c;
            Ws[k][c] = (k < kb && gc < OUT) ? W[(size_t)(k0 + k)*OUT + gc] : 0.f;
        }
        __syncthreads();
        #pragma unroll 8
        for (int k = 0; k < 64; ++k){
            float4 w4 = *(const float4*)&Ws[k][c0];
            #pragma unroll
            for (int i = 0; i < 4; ++i){
                float xv = Xs[r0+i][k];
                acc[i][0] = fmaf(xv, w4.x, acc[i][0]);
                acc[i][1] = fmaf(xv, w4.y, acc[i][1]);
                acc[i][2] = fmaf(xv, w4.z, acc[i][2]);
                acc[i][3] = fmaf(xv, w4.w, acc[i][3]);
            }
        }
        __syncthreads();
    }
    #pragma unroll
    for (int i = 0; i < 4; ++i){
        int gr = row0 + r0 + i;
        if (gr >= NNODE) continue;
        #pragma unroll
        for (int j = 0; j < 4; ++j){
            int gc = col0 + c0 + j;
            if (gc < OUT) Y[(size_t)gr*OUT + gc] = acc[i][j] + B[gc];
        }
    }
}

// ---- GATv2 layer 1: H=12, C=12 (144 ch). 192 thr = 12 heads x 16 lanes ---
// Writes output in place into xr (each block only touches its own row).
__global__ __launch_bounds__(192) void gat1_kernel(const float* __restrict__ xl,
                                                   float* __restrict__ xr,
                                                   const int* __restrict__ col,
                                                   const int* __restrict__ cnt,
                                                   const float* __restrict__ att,
                                                   const float* __restrict__ bias){
    int d = blockIdx.x;
    int t = threadIdx.x;
    int c16 = t & 15;
    int hgrp = t >> 4;             // head 0..11
    bool act = c16 < 12;
    int ch = hgrp*12 + c16;        // valid when act
    __shared__ int scol[CAP];
    int degd = min(cnt[d], CAP);
    if (t < degd) scol[t] = col[d*CAP + t];
    float xrv  = act ? xr[(size_t)d*144 + ch] : 0.f;
    float attv = act ? att[ch] : 0.f;
    float xlv  = act ? xl[(size_t)d*144 + ch] : 0.f;
    __syncthreads();
    // self loop
    float p = lrelu(xlv + xrv) * attv;
    p += __shfl_xor(p,1); p += __shfl_xor(p,2); p += __shfl_xor(p,4); p += __shfl_xor(p,8);
    float m = p, l = 1.f, acc = xlv;
    for (int k = 0; k < degd; ++k){
        int s = scol[k];
        float xv = act ? xl[(size_t)s*144 + ch] : 0.f;
        float q = lrelu(xv + xrv) * attv;
        q += __shfl_xor(q,1); q += __shfl_xor(q,2); q += __shfl_xor(q,4); q += __shfl_xor(q,8);
        float nm = fmaxf(m, q);
        float eo = __expf(m - nm);
        float en = __expf(q - nm);
        l = fmaf(l, eo, en);
        acc = fmaf(acc, eo, en * xv);
        m = nm;
    }
    if (act) xr[(size_t)d*144 + ch] = acc / (l + 1e-16f) + bias[ch];
}

// ---- GATv2 layer 2: H=1, C=64. 1 wave per node, 4 nodes/block ------------
__global__ __launch_bounds__(256) void gat2_kernel(const float* __restrict__ xl,
                                                   const float* __restrict__ xr,
                                                   const int* __restrict__ col,
                                                   const int* __restrict__ cnt,
                                                   const float* __restrict__ att,
                                                   const float* __restrict__ bias,
                                                   float* __restrict__ out){
    int wid = threadIdx.x >> 6, lane = threadIdx.x & 63;
    int d = blockIdx.x * 4 + wid;
    float xrv  = xr[(size_t)d*64 + lane];
    float attv = att[lane];
    float xlv  = xl[(size_t)d*64 + lane];
    int degd = min(cnt[d], CAP);
    int myc = (lane < degd) ? col[d*CAP + lane] : 0;
    float p = lrelu(xlv + xrv) * attv;
    #pragma unroll
    for (int msk = 1; msk < 64; msk <<= 1) p += __shfl_xor(p, msk);
    float m = p, l = 1.f, acc = xlv;
    for (int k = 0; k < degd; ++k){
        int s = __shfl(myc, k);
        float xv = xl[(size_t)s*64 + lane];
        float q = lrelu(xv + xrv) * attv;
        #pragma unroll
        for (int msk = 1; msk < 64; msk <<= 1) q += __shfl_xor(q, msk);
        float nm = fmaxf(m, q);
        float eo = __expf(m - nm);
        float en = __expf(q - nm);
        l = fmaf(l, eo, en);
        acc = fmaf(acc, eo, en * xv);
        m = nm;
    }
    out[(size_t)d*64 + lane] = acc / (l + 1e-16f) + bias[lane];
}

extern "C" void kernel_launch(void* const* d_in, const int* in_sizes, int n_in,
                              void* d_out, int out_size, void* d_ws, size_t ws_size,
                              hipStream_t stream){
    const float* feat  = (const float*)d_in[0];
    const int*   ei    = (const int*)d_in[1];
    const float* W_ssg = (const float*)d_in[2];
    const float* b_ssg = (const float*)d_in[3];
    const float* W1l   = (const float*)d_in[4];
    const float* b1l   = (const float*)d_in[5];
    const float* W1r   = (const float*)d_in[6];
    const float* b1r   = (const float*)d_in[7];
    const float* att1  = (const float*)d_in[8];
    const float* bias1 = (const float*)d_in[9];
    const float* W2l   = (const float*)d_in[10];
    const float* b2l   = (const float*)d_in[11];
    const float* W2r   = (const float*)d_in[12];
    const float* b2r   = (const float*)d_in[13];
    const float* att2  = (const float*)d_in[14];
    const float* bias2 = (const float*)d_in[15];
    float* out = (float*)d_out;

    char* ws = (char*)d_ws;
    size_t off = 0;
    auto alloc = [&](size_t bytes)->void*{
        void* p = ws + off; off = (off + bytes + 255) & ~(size_t)255; return p;
    };
    int*   flag = (int*)  alloc(4);
    int*   cnt  = (int*)  alloc((size_t)NNODE*4);
    int*   col  = (int*)  alloc((size_t)NNODE*CAP*4);
    float* dinv = (float*)alloc((size_t)NNODE*4);
    float* h    = (float*)alloc((size_t)NNODE*64*4);
    float* x1   = (float*)alloc((size_t)NNODE*64*4);
    float* xl1  = (float*)alloc((size_t)NNODE*144*4);
    float* xr1  = (float*)alloc((size_t)NNODE*144*4);
    float* xl2  = h;    // reuse (h dead after gemm1)
    float* xr2  = x1;   // reuse (x1 dead after gemm2a/b)

    hipMemsetAsync(cnt, 0, (size_t)NNODE*4, stream);
    detect_kernel<<<1, 64, 0, stream>>>(ei, flag);
    scatter_kernel<<<(NEDGE + 255)/256, 256, 0, stream>>>(ei, flag, cnt, col);
    dinv_kernel<<<(NNODE + 255)/256, 256, 0, stream>>>(cnt, dinv);

    ssg_kernel<<<NNODE/4, 256, 0, stream>>>(feat, col, cnt, dinv, h);

    dim3 g1((NNODE + 63)/64, 1);
    gemm_kernel<64,64><<<g1, 256, 0, stream>>>(h, W_ssg, b_ssg, x1);

    dim3 g2((NNODE + 63)/64, 3);
    gemm_kernel<64,144><<<g2, 256, 0, stream>>>(x1, W1l, b1l, xl1);
    gemm_kernel<64,144><<<g2, 256, 0, stream>>>(x1, W1r, b1r, xr1);

    gat1_kernel<<<NNODE, 192, 0, stream>>>(xl1, xr1, col, cnt, att1, bias1);

    dim3 g3((NNODE + 63)/64, 1);
    gemm_kernel<144,64><<<g3, 256, 0, stream>>>(xr1, W2l, b2l, xl2);
    gemm_kernel<144,64><<<g3, 256, 0, stream>>>(xr1, W2r, b2r, xr2);

    gat2_kernel<<<NNODE/4, 256, 0, stream>>>(xl2, xr2, col, cnt, att2, bias2, out);
}